// Round 18
// baseline (98.704 us; speedup 1.0000x reference)
//
#include <hip/hip_runtime.h>

#define CIN   256
#define COUT  256
#define HH    64
#define WW    64
#define KD    2304         // CIN * 9
#define NPIX  16384        // B * HO * WO
#define SPLIT 16
#define CPS   (CIN / SPLIT)
#define NSTEP 72           // full K = 2304 = 72 x 32 (no K-split)

typedef __attribute__((ext_vector_type(4))) float  float4v;
typedef __attribute__((ext_vector_type(4))) unsigned int uint4v;
typedef _Float16 h2 __attribute__((ext_vector_type(2)));
typedef _Float16 h8 __attribute__((ext_vector_type(8)));
typedef unsigned int u32;
typedef unsigned short u16;

__device__ __forceinline__ h2 as_h2(u32 v) { union { u32 u; h2 h; } x; x.u = v; return x.h; }
__device__ __forceinline__ u32 as_u32(h2 h) { union { u32 u; h2 h; } x; x.h = h; return x.u; }
__device__ __forceinline__ u16 f2h_bits(float f) { _Float16 h = (_Float16)f; return *(u16*)&h; }
__device__ __forceinline__ u32 packh2(float a, float b) {
  h2 h; h[0] = (_Float16)a; h[1] = (_Float16)b; return as_u32(h);
}

__device__ __forceinline__ void gload_lds16(const void* g, void* l) {
  __builtin_amdgcn_global_load_lds((const __attribute__((address_space(1))) u32*)g,
                                   (__attribute__((address_space(3))) u32*)l, 16, 0, 0);
}

// ---------------- Kernel 1a: offset/mask partials (f16-packed) + xt emission ----------------
__global__ __launch_bounds__(256) void offmask_part_kernel(
    const float* __restrict__ x,
    const float* __restrict__ off_dw, const float* __restrict__ off_pw,
    const float* __restrict__ mask_dw, const float* __restrict__ mask_pw,
    u32* __restrict__ part2, u16* __restrict__ xt)
{
  int m = blockIdx.x * 256 + threadIdx.x;
  int s = blockIdx.y;
  int b = m >> 12, pix = m & 4095;
  int ho = pix >> 6, wo = pix & 63;
  const float* xb = x + (size_t)b * CIN * 4096;

  float acc[27];
#pragma unroll
  for (int j = 0; j < 27; ++j) acc[j] = 0.f;
  u16 ctr[16];

  int c0 = s * CPS;
  for (int ci = 0; ci < CPS; ++ci) {
    int c = c0 + ci;
    const float* xc = xb + (size_t)c * 4096;
    float d_off = 0.f, d_msk = 0.f;
#pragma unroll
    for (int t = 0; t < 9; ++t) {
      int gy = ho + t / 3 - 1, gx = wo + t % 3 - 1;
      bool ok = (gy >= 0) & (gy < HH) & (gx >= 0) & (gx < WW);
      float v = ok ? xc[gy * 64 + gx] : 0.f;
      if (t == 4) ctr[ci] = f2h_bits(v);
      d_off += v * off_dw[c * 9 + t];
      d_msk += v * mask_dw[c * 9 + t];
    }
#pragma unroll
    for (int j = 0; j < 18; ++j) acc[j] += d_off * off_pw[j * 256 + c];
#pragma unroll
    for (int j = 0; j < 9; ++j) acc[18 + j] += d_msk * mask_pw[j * 256 + c];
  }
  *(uint4v*)(xt + (size_t)m * 256 + c0)     = *(uint4v*)&ctr[0];
  *(uint4v*)(xt + (size_t)m * 256 + c0 + 8) = *(uint4v*)&ctr[8];

  uint4v o[4];
#pragma unroll
  for (int k = 0; k < 13; ++k) o[k >> 2][k & 3] = packh2(acc[2 * k], acc[2 * k + 1]);
  o[3][1] = packh2(acc[26], 0.f);
  o[3][2] = 0; o[3][3] = 0;
  uint4v* pp = (uint4v*)(part2 + ((size_t)s * NPIX + m) * 16);
#pragma unroll
  for (int q = 0; q < 4; ++q) pp[q] = o[q];
}

// ---------------- Kernel 1b: reduce f16 partials -> rec f32 ----------------
__global__ __launch_bounds__(256) void offmask_reduce_kernel(
    const u32* __restrict__ part2, float* __restrict__ rec)
{
  int i = blockIdx.x * 256 + threadIdx.x;   // over NPIX*16
  int m = i >> 4, k = i & 15;
  int j0 = 2 * k, j1 = 2 * k + 1;
  if (j0 >= 27) { rec[(size_t)m * 32 + j0] = 0.f; rec[(size_t)m * 32 + j1] = 0.f; return; }
  float s0 = 0.f, s1 = 0.f;
#pragma unroll
  for (int s = 0; s < SPLIT; ++s) {
    h2 v = as_h2(part2[((size_t)s * NPIX + m) * 16 + k]);
    s0 += (float)v[0]; s1 += (float)v[1];
  }
  rec[(size_t)m * 32 + j0] = (j0 < 18) ? s0 : 2.f / (1.f + __expf(-s0));
  rec[(size_t)m * 32 + j1] = (j1 < 18) ? s1 : ((j1 < 27) ? 2.f / (1.f + __expf(-s1)) : 0.f);
}

// ---------------- Kernel 2: weight f32 -> f16 [co][kk*256 + c] ----------------
__global__ __launch_bounds__(256) void wconv_kernel(const float* __restrict__ w,
                                                    u16* __restrict__ wb)
{
  int i = blockIdx.x * 256 + threadIdx.x;
  int co = i / KD, rem = i - co * KD;
  int c = rem / 9, kk = rem - c * 9;
  wb[co * KD + kk * 256 + c] = f2h_bits(w[i]);
}

// ---------------- Kernel 4: FUSED im2col+GEMM, B-OPERAND IN REGISTERS ----------------
// Wave owns 16 pixels; lane (kq,rl) samples 8 channels (kq*8..) of its own
// pixel (rl) -> the blended result IS the MFMA B-fragment. No lB, no ds_write,
// no B barrier dependency. Only W is LDS-staged (3x16KB tbuf, 2-deep gload_lds
// prefetch, counted vmcnt(4)). Full K=2304 per wave (72 steps x 16 MFMA) ->
// no K-split, no tmp, no add kernel; direct f32+bias store.
// Per step: BLEND(sv->bf) -> [corners] -> SAMP S(t+1)->sv -> DMA A(t+2) ->
// 16x{ds_read af, MFMA} -> vmcnt(4) [drains S(t+1)+A(t+1), keeps A(t+2)] ->
// lgkmcnt(0) -> s_barrier. Swizzle on W (proven): slot^ (r&3)^((r>>2)&3).
__global__ __launch_bounds__(256) void gemm_fused_kernel(
    const u16* __restrict__ A,     // wb f16 [COUT][KD]
    const u16* __restrict__ xt,    // NHWC f16 [B*4096][256]
    const float* __restrict__ rec, // [NPIX][32]
    const float* __restrict__ bias,
    float* __restrict__ out)
{
  __shared__ __align__(16) u16 lA[3][256 * 32];   // 3 x 16 KB
  const int tid = threadIdx.x;
  const int ptile = blockIdx.x;          // 0..255 (64-px tiles)
  const int m0 = ptile * 64;
  const int b_img = ptile >> 6;
  const int wave = tid >> 6, lane = tid & 63;
  const int rl = lane & 15, kq = lane >> 4;
  const int sA = (kq ^ (rl & 3) ^ ((rl >> 2) & 3)) * 8;

  // W staging: 256 threads x 4 gload_lds cover 256 rows x 4 slots
  const int rA  = tid >> 2;              // 0..63
  const int koA = ((tid & 3) ^ (rA & 3) ^ ((rA >> 2) & 3)) * 8;
  const u16* aRow[4];
#pragma unroll
  for (int q = 0; q < 4; ++q) aRow[q] = A + (size_t)(rA + q * 64) * KD + koA;

  // per-lane pixel for B sampling
  const int m_px = m0 + wave * 16 + rl;
  const int ho = (m_px & 4095) >> 6, wo = m_px & 63;
  const float* rp = rec + (size_t)m_px * 32;
  const u16* xb = xt + (size_t)b_img * 4096 * 256;

  u32 cOff[4];
  h2  wh[4];
  uint4v sv[4];                          // 4 corners x 8 channels (f16)

#define KCOL(t_) (((t_) >> 3) * 256 + ((t_) & 7) * 32)

#define CALC_CORNERS(kk_) do {                                             \
    float dy = rp[(kk_) * 2], dx = rp[(kk_) * 2 + 1], msk = rp[18 + (kk_)];\
    float py  = (float)(ho - 1 + ((kk_) / 3)) + dy;                        \
    float pxf = (float)(wo - 1 + ((kk_) % 3)) + dx;                        \
    float fy = floorf(py), fx = floorf(pxf);                               \
    int y0 = (int)fy, x0 = (int)fx;                                        \
    float wy1 = py - fy, wy0 = 1.f - wy1;                                  \
    float wx1 = pxf - fx, wx0 = 1.f - wx1;                                 \
    _Pragma("unroll")                                                      \
    for (int cr = 0; cr < 4; ++cr) {                                       \
      int iy = y0 + (cr >> 1), ix = x0 + (cr & 1);                         \
      bool valid = (iy >= 0) & (iy < HH) & (ix >= 0) & (ix < WW);          \
      int iyc = min(max(iy, 0), HH - 1), ixc = min(max(ix, 0), WW - 1);    \
      cOff[cr] = (u32)(iyc * 64 + ixc) * 256;                              \
      float wy = (cr >> 1) ? wy1 : wy0;                                    \
      float wx = (cr & 1) ? wx1 : wx0;                                     \
      float wf = valid ? (wy * wx * msk) : 0.f;                            \
      _Float16 hw = (_Float16)wf;                                          \
      wh[cr] = (h2){hw, hw};                                               \
    }                                                                      \
  } while (0)

#define STAGE_A(k_, sl_) do {                                              \
    int k0_ = KCOL(k_);                                                    \
    _Pragma("unroll")                                                      \
    for (int q = 0; q < 4; ++q)                                            \
      gload_lds16(aRow[q] + k0_, lA[sl_] + q * 2048 + tid * 8);            \
  } while (0)

#define SAMP(t_) do {                                                      \
    int c0_ = ((t_) & 7) * 32 + kq * 8;                                    \
    _Pragma("unroll")                                                      \
    for (int cr = 0; cr < 4; ++cr)                                         \
      sv[cr] = *(const uint4v*)(xb + cOff[cr] + c0_);                      \
  } while (0)

#define BLEND(bf_) do {                                                    \
    _Pragma("unroll")                                                      \
    for (int w_ = 0; w_ < 4; ++w_) {                                       \
      h2 s_ = wh[0] * as_h2(sv[0][w_]) + wh[1] * as_h2(sv[1][w_]);         \
      s_   += wh[2] * as_h2(sv[2][w_]) + wh[3] * as_h2(sv[3][w_]);         \
      ((u32*)&(bf_))[w_] = as_u32(s_);                                     \
    }                                                                      \
  } while (0)

  float4v acc[16];
#pragma unroll
  for (int m = 0; m < 16; ++m) acc[m] = float4v{0.f, 0.f, 0.f, 0.f};

  // ---- prologue: S(0)[4] -> A(0)[4] -> A(1)[4]; vmcnt(4) drains S(0)+A(0) ----
  {
    CALC_CORNERS(0);
    SAMP(0);
    STAGE_A(0, 0);
    STAGE_A(1, 1);
    asm volatile("s_waitcnt vmcnt(4)" ::: "memory");
    __builtin_amdgcn_s_barrier();
  }

  int sl = 0;                             // = t % 3
  for (int t = 0; t < NSTEP; ++t) {
    // B-fragment for step t (sv holds S(t), drained by previous vmcnt)
    h8 bf;
    BLEND(bf);
    // issue S(t+1) (wh updated first if tap changes; pairing stays correct)
    const int tn = (t + 1 == NSTEP) ? 0 : t + 1;
    if ((tn & 7) == 0) CALC_CORNERS(tn >> 3);
    SAMP(tn);                             // vmcnt +4
    // issue A(t+2) into slot (t+2)%3
    const int tn2 = (t + 2 >= NSTEP) ? (t + 2 - NSTEP) : t + 2;
    const int sl2 = (sl >= 1) ? sl - 1 : 2;
    STAGE_A(tn2, sl2);                    // vmcnt +4
    // W frags + MFMA on step t
    const u16* laP = lA[0] + sl * (256 * 32);
#pragma unroll
    for (int half = 0; half < 2; ++half) {
      h8 af[8];
#pragma unroll
      for (int m = 0; m < 8; ++m)
        af[m] = *(const h8*)&laP[(half * 128 + m * 16 + rl) * 32 + sA];
#pragma unroll
      for (int m = 0; m < 8; ++m)
        acc[half * 8 + m] =
            __builtin_amdgcn_mfma_f32_16x16x32_f16(af[m], bf, acc[half * 8 + m], 0, 0, 0);
    }
    // drain S(t+1)+A(t+1); A(t+2) stays in flight across the barrier
    asm volatile("s_waitcnt vmcnt(4)" ::: "memory");
    asm volatile("s_waitcnt lgkmcnt(0)" ::: "memory");
    __builtin_amdgcn_s_barrier();
    sl = (sl == 2) ? 0 : sl + 1;
  }
#undef STAGE_A
#undef CALC_CORNERS
#undef SAMP
#undef BLEND
#undef KCOL

  // epilogue: direct f32 + bias store (each element written exactly once)
  float* ob = out + (size_t)b_img * COUT * 4096;
  const int px = (m0 & 4095) + wave * 16 + rl;
#pragma unroll
  for (int m = 0; m < 16; ++m) {
    int co_base = (m >> 3) * 128 + (m & 7) * 16 + kq * 4;
#pragma unroll
    for (int j = 0; j < 4; ++j) {
      int co = co_base + j;
      ob[(size_t)co * 4096 + px] = acc[m][j] + bias[co];
    }
  }
}

extern "C" void kernel_launch(void* const* d_in, const int* in_sizes, int n_in,
                              void* d_out, int out_size, void* d_ws, size_t ws_size,
                              hipStream_t stream) {
  const float* x       = (const float*)d_in[0];
  const float* weight  = (const float*)d_in[1];
  const float* bias    = (const float*)d_in[2];
  const float* off_dw  = (const float*)d_in[3];
  const float* off_pw  = (const float*)d_in[4];
  const float* mask_dw = (const float*)d_in[5];
  const float* mask_pw = (const float*)d_in[6];

  // ws layout: rec 2MB @0 | wb 1.18MB @2,097,152 | xt 8.39MB @3,276,800 |
  //            part2 16.78MB @11,665,408  => total 28,442,624 B
  if (ws_size < 28442624ull) return;
  float* rec   = (float*)d_ws;
  u16*   wb    = (u16*)((char*)d_ws + 2097152);
  u16*   xt    = (u16*)((char*)d_ws + 3276800);
  u32*   part2 = (u32*)((char*)d_ws + 11665408);
  float* out   = (float*)d_out;

  wconv_kernel<<<dim3(2304), dim3(256), 0, stream>>>(weight, wb);
  offmask_part_kernel<<<dim3(NPIX / 256, SPLIT), dim3(256), 0, stream>>>(
      x, off_dw, off_pw, mask_dw, mask_pw, part2, xt);
  offmask_reduce_kernel<<<dim3(NPIX * 16 / 256), dim3(256), 0, stream>>>(part2, rec);
  gemm_fused_kernel<<<dim3(256), dim3(256), 0, stream>>>(wb, xt, rec, bias, out);
}